// Round 1
// baseline (3595.319 us; speedup 1.0000x reference)
//
#include <hip/hip_runtime.h>
#include <math.h>

#define NB 64      // batch
#define NCH 64     // channels C
#define NT 4096    // time
#define TT2 64     // block-kernel time tile

__device__ __forceinline__ float fast_rcp(float x) { return __builtin_amdgcn_rcpf(x); }
__device__ __forceinline__ float fast_sigmoid(float x) { return fast_rcp(1.0f + __expf(-x)); }
__device__ __forceinline__ float fast_tanh(float x) {
    // tanh(x) = 1 - 2/(exp(2x)+1); exp overflow -> rcp(inf)=0 -> 1, graceful
    return 1.0f - 2.0f * fast_rcp(__expf(2.0f * x) + 1.0f);
}

// -------- input conv (K=2, dil=1, in=[x, linspace]) + acc init --------
__global__ __launch_bounds__(256) void k_conv_in(
    const float* __restrict__ x, const float* __restrict__ w_in,
    const float* __restrict__ b_in, float* __restrict__ h, float* __restrict__ acc)
{
    const int b = blockIdx.x;
    const int t = blockIdx.y * 256 + threadIdx.x;
    const float inv = 1.0f / 4095.0f;   // linspace(0, 1, 4096) step
    const float x1 = x[b * NT + t];
    const float x0 = (t > 0) ? x[b * NT + t - 1] : 0.0f;
    const float l1 = (float)t * inv;
    const float l0 = (t > 0) ? (float)(t - 1) * inv : 0.0f;
    for (int c = 0; c < NCH; ++c) {
        // w_in layout [C][2][2]: c*4 + ci*2 + k ; tap k=0 -> t-1, k=1 -> t
        float v = b_in[c] + w_in[c*4+0]*x0 + w_in[c*4+1]*x1
                          + w_in[c*4+2]*l0 + w_in[c*4+3]*l1;
        h[(size_t)(b*NCH + c)*NT + t] = v;
        acc[(size_t)(b*NCH + c)*NT + t] = v;
    }
}

// -------- one residual block: dilated conv K=2 -> gate -> 1x1 -> +res, acc += h --------
// block = (batch, 64-t tile); 256 threads = 4 waves; wave q owns output channels [16q,16q+16)
__global__ __launch_bounds__(256) void k_block(
    const float* __restrict__ w1, const float* __restrict__ b1,
    const float* __restrict__ w2, const float* __restrict__ b2,
    const float* __restrict__ hin, float* __restrict__ hout,
    float* __restrict__ acc, int d)
{
    __shared__ float hs[NCH][TT2 + 128];   // input tile + halo (max dil 128): 49152 B
    __shared__ float gbuf[NCH][TT2];       // gated activations: 16384 B
    const int b   = blockIdx.x;
    const int t0  = blockIdx.y * TT2;
    const int tid = threadIdx.x;
    const int q   = __builtin_amdgcn_readfirstlane(tid >> 6);  // wave-uniform group id
    const int tt  = tid & 63;
    const int W   = TT2 + d;

    // ---- stage hin[t0-d .. t0+63] for all 64 channels (zeros left of t=0) ----
    {
        const int lr = tid >> 6, lj = tid & 63;
        for (int c = lr; c < NCH; c += 4) {
            const float* src = hin + (size_t)(b*NCH + c)*NT + (t0 - d);
            for (int j = lj; j < W; j += 64)
                hs[c][j] = (t0 - d + j >= 0) ? src[j] : 0.0f;
        }
    }
    __syncthreads();

    // ---- phase 1: a[co] = sum_ci w1[co][ci][0]*h[t-d] + w1[co][ci][1]*h[t]; gate ----
    {
        float at[16], as[16];
        #pragma unroll
        for (int i = 0; i < 16; ++i) { at[i] = 0.0f; as[i] = 0.0f; }
        for (int ci = 0; ci < NCH; ++ci) {
            const float h0 = hs[ci][tt];       // tap at t-d
            const float h1 = hs[ci][tt + d];   // tap at t
            const float* wr = w1 + q*16*128 + ci*2;  // w1 layout [128][64][2]
            #pragma unroll
            for (int i = 0; i < 16; ++i) {
                at[i] += wr[i*128       ]*h0 + wr[i*128 + 1   ]*h1;  // tanh half (co = q*16+i)
                as[i] += wr[i*128 + 8192]*h0 + wr[i*128 + 8193]*h1;  // sigm half (co+64)
            }
        }
        #pragma unroll
        for (int i = 0; i < 16; ++i) {
            const int c = q*16 + i;
            gbuf[c][tt] = fast_tanh(at[i] + b1[c]) * fast_sigmoid(as[i] + b1[c + 64]);
        }
    }
    __syncthreads();

    // ---- phase 2: 1x1 conv + residual + acc ----
    {
        const int t = t0 + tt;
        float o[16];
        #pragma unroll
        for (int i = 0; i < 16; ++i) o[i] = b2[q*16 + i];
        for (int ci = 0; ci < NCH; ++ci) {
            const float gv = gbuf[ci][tt];
            const float* wr = w2 + (q*16)*NCH + ci;   // w2 layout [64][64]
            #pragma unroll
            for (int i = 0; i < 16; ++i) o[i] += wr[i*NCH]*gv;
        }
        #pragma unroll
        for (int i = 0; i < 16; ++i) {
            const int c = q*16 + i;
            const float hn = o[i] + hs[c][tt + d];    // residual from staged input
            hout[(size_t)(b*NCH + c)*NT + t] = hn;
            acc [(size_t)(b*NCH + c)*NT + t] += hn;
        }
    }
}

// -------- head: agg=relu(acc/9); z=W_mid@agg; pi/mu/sigma --------
__global__ __launch_bounds__(256) void k_head(
    const float* __restrict__ acc,
    const float* __restrict__ w_mid, const float* __restrict__ b_mid,
    const float* __restrict__ w_pi,  const float* __restrict__ b_pi,
    const float* __restrict__ w_mu,  const float* __restrict__ b_mu,
    const float* __restrict__ w_sg,  const float* __restrict__ b_sg,
    float* __restrict__ out)
{
    __shared__ float aggs[NCH][256];   // 64 KB
    const int b   = blockIdx.x;
    const int tid = threadIdx.x;
    const int t   = blockIdx.y * 256 + tid;
    const float inv9 = 1.0f / 9.0f;
    for (int c = 0; c < NCH; ++c) {
        float v = acc[(size_t)(b*NCH + c)*NT + t] * inv9;
        aggs[c][tid] = v > 0.0f ? v : 0.0f;
    }
    __syncthreads();

    float hd[10];
    #pragma unroll
    for (int o = 0; o < 10; ++o) hd[o] = 0.0f;

    for (int zc = 0; zc < 8; ++zc) {           // z in chunks of 16 (z has 128 ch)
        float z[16];
        #pragma unroll
        for (int i = 0; i < 16; ++i) z[i] = b_mid[zc*16 + i];
        for (int c = 0; c < NCH; ++c) {
            const float a = aggs[c][tid];
            const float* wr = w_mid + (zc*16)*NCH + c;  // [128][64]
            #pragma unroll
            for (int i = 0; i < 16; ++i) z[i] += wr[i*NCH]*a;
        }
        #pragma unroll
        for (int i = 0; i < 16; ++i) {
            const int j = zc*16 + i;
            #pragma unroll
            for (int o = 0; o < 4; ++o) hd[o] += w_pi[o*128 + j]*z[i];
            #pragma unroll
            for (int o = 0; o < 3; ++o) {
                hd[4+o] += w_mu[o*128 + j]*z[i];
                hd[7+o] += w_sg[o*128 + j]*z[i];
            }
        }
    }

    // pi = softmax over 4
    const float p0 = hd[0] + b_pi[0], p1 = hd[1] + b_pi[1];
    const float p2 = hd[2] + b_pi[2], p3 = hd[3] + b_pi[3];
    const float m  = fmaxf(fmaxf(p0, p1), fmaxf(p2, p3));
    const float e0 = __expf(p0 - m), e1 = __expf(p1 - m);
    const float e2 = __expf(p2 - m), e3 = __expf(p3 - m);
    const float rs = fast_rcp(e0 + e1 + e2 + e3);
    const size_t piBase = (size_t)(b*4)*NT + t;
    out[piBase        ] = e0*rs;
    out[piBase +   NT ] = e1*rs;
    out[piBase + 2*NT ] = e2*rs;
    out[piBase + 3*NT ] = e3*rs;

    float* muO = out + (size_t)NB*4*NT;
    float* sgO = out + (size_t)NB*7*NT;
    #pragma unroll
    for (int o = 0; o < 3; ++o) {
        const float mv = hd[4+o] + b_mu[o];
        muO[(size_t)(b*3+o)*NT + t] = 2.0f * fast_tanh(0.5f * mv);
        const float sv = hd[7+o] + b_sg[o];
        // softplus
        sgO[(size_t)(b*3+o)*NT + t] = (sv > 15.0f) ? sv : logf(1.0f + __expf(sv));
    }
}

extern "C" void kernel_launch(void* const* d_in, const int* in_sizes, int n_in,
                              void* d_out, int out_size, void* d_ws, size_t ws_size,
                              hipStream_t stream)
{
    const float* x     = (const float*)d_in[0];
    const float* w_in  = (const float*)d_in[1];
    const float* b_in  = (const float*)d_in[2];
    const float* bw1   = (const float*)d_in[3];   // [8][128][64][2]
    const float* bb1   = (const float*)d_in[4];   // [8][128]
    const float* bw2   = (const float*)d_in[5];   // [8][64][64][1]
    const float* bb2   = (const float*)d_in[6];   // [8][64]
    const float* w_mid = (const float*)d_in[7];
    const float* b_mid = (const float*)d_in[8];
    const float* w_pi  = (const float*)d_in[9];
    const float* b_pi  = (const float*)d_in[10];
    const float* w_mu  = (const float*)d_in[11];
    const float* b_mu  = (const float*)d_in[12];
    const float* w_sg  = (const float*)d_in[13];
    const float* b_sg  = (const float*)d_in[14];
    float* out = (float*)d_out;

    const size_t tensSz = (size_t)NB * NCH * NT;  // 16,777,216 floats = 64 MB
    float* hA  = (float*)d_ws;
    float* hB  = hA + tensSz;
    float* acc = hB + tensSz;                     // total ws use: 192 MB

    k_conv_in<<<dim3(NB, 16), 256, 0, stream>>>(x, w_in, b_in, hA, acc);

    static const int dil[8] = {1, 2, 4, 8, 16, 32, 64, 128};
    float* hin = hA; float* hout = hB;
    for (int i = 0; i < 8; ++i) {
        k_block<<<dim3(NB, 64), 256, 0, stream>>>(
            bw1 + (size_t)i*128*64*2, bb1 + i*128,
            bw2 + (size_t)i*64*64,    bb2 + i*64,
            hin, hout, acc, dil[i]);
        float* tmp = hin; hin = hout; hout = tmp;
    }

    k_head<<<dim3(NB, 16), 256, 0, stream>>>(acc, w_mid, b_mid, w_pi, b_pi,
                                             w_mu, b_mu, w_sg, b_sg, out);
}

// Round 2
// 882.167 us; speedup vs baseline: 4.0756x; 4.0756x over previous
//
#include <hip/hip_runtime.h>
#include <math.h>

#define NB 64      // batch
#define NCH 64     // channels C
#define NT 4096    // time
#define TT 128     // k_block time tile

typedef float f32x4 __attribute__((ext_vector_type(4)));
typedef short s16x8 __attribute__((ext_vector_type(8)));

__device__ __forceinline__ float fast_rcp(float x) { return __builtin_amdgcn_rcpf(x); }
__device__ __forceinline__ float fast_sigmoid(float x) { return fast_rcp(1.0f + __expf(-x)); }
__device__ __forceinline__ float fast_tanh(float x) {
    return 1.0f - 2.0f * fast_rcp(__expf(2.0f * x) + 1.0f);
}
__device__ __forceinline__ unsigned short f2bf(float f) {   // RNE float->bf16
    unsigned int u = __builtin_bit_cast(unsigned int, f);
    u += 0x7fffu + ((u >> 16) & 1u);
    return (unsigned short)(u >> 16);
}

// swizzled LDS byte offset: row stride 128B, XOR bits 4-6 with row&7 (G4 fix)
#define HSW(j, cb) ((j)*128 + ((cb) ^ (((j)&7) << 4)))

// -------- weight pre-pack: fragment-ordered bf16 (runs every launch) --------
// w1p: [L][wave4][mi2][ks4][lane64][8]  A[co][k], co=16w+(l&15)+64mi, k=32ks+8(l>>4)+j
//      k = ci + 64*tap  (ci = k&63, tap = k>>6)
// w2p: [L][wave4][ks2][lane64][8]       A[co][ci], co=16w+(l&15), ci=32ks+8(l>>4)+j
__global__ __launch_bounds__(256) void k_pack(
    const float* __restrict__ bw1, const float* __restrict__ bw2,
    short* __restrict__ w1p, short* __restrict__ w2p)
{
    const int id = blockIdx.x * 256 + threadIdx.x;
    if (id < 16384) {
        const int l = id & 63, ks = (id >> 6) & 3, mi = (id >> 8) & 1,
                  w = (id >> 9) & 3, L = id >> 11;
        const int co = 16*w + (l & 15) + 64*mi;
        short v[8];
        #pragma unroll
        for (int j = 0; j < 8; ++j) {
            const int k = 32*ks + 8*(l >> 4) + j;
            const int ci = k & 63, tap = k >> 6;
            v[j] = (short)f2bf(bw1[((size_t)(L*128 + co)*64 + ci)*2 + tap]);
        }
        *(s16x8*)(w1p + (size_t)id*8) = *(const s16x8*)v;
    } else if (id < 16384 + 4096) {
        const int id2 = id - 16384;
        const int l = id2 & 63, ks = (id2 >> 6) & 1, w = (id2 >> 7) & 3, L = id2 >> 9;
        const int co = 16*w + (l & 15);
        short v[8];
        #pragma unroll
        for (int j = 0; j < 8; ++j) {
            const int ci = 32*ks + 8*(l >> 4) + j;
            v[j] = (short)f2bf(bw2[(size_t)(L*64 + co)*64 + ci]);
        }
        *(s16x8*)(w2p + (size_t)id2*8) = *(const s16x8*)v;
    }
}

// -------- input conv (K=2, dil=1, in=[x, linspace]) + acc init --------
__global__ __launch_bounds__(256) void k_conv_in(
    const float* __restrict__ x, const float* __restrict__ w_in,
    const float* __restrict__ b_in, float* __restrict__ h, float* __restrict__ acc)
{
    const int b = blockIdx.x;
    const int t = blockIdx.y * 256 + threadIdx.x;
    const float inv = 1.0f / 4095.0f;
    const float x1 = x[b * NT + t];
    const float x0 = (t > 0) ? x[b * NT + t - 1] : 0.0f;
    const float l1 = (float)t * inv;
    const float l0 = (t > 0) ? (float)(t - 1) * inv : 0.0f;
    for (int c = 0; c < NCH; ++c) {
        float v = b_in[c] + w_in[c*4+0]*x0 + w_in[c*4+1]*x1
                          + w_in[c*4+2]*l0 + w_in[c*4+3]*l1;
        h[(size_t)(b*NCH + c)*NT + t] = v;
        acc[(size_t)(b*NCH + c)*NT + t] = v;
    }
}

// -------- residual block via MFMA --------
// block=(batch, 128-t tile), 256 thr = 4 waves.
// phase1: a[128][128t] = W1[128][K=128] @ Xt[K][128t], K: ci+64*tap (tap0=t-d, tap1=t)
// wave w owns a-rows {16w..16w+16} (tanh, mi=0) and {64+16w..} (sigm, mi=1)
// phase2: out[64][128t] = W2[64][64] @ gated[64][128t]; wave w owns rows 16w..16w+16
__global__ __launch_bounds__(256, 3) void k_block(
    const short* __restrict__ w1p, const float* __restrict__ b1,
    const short* __restrict__ w2p, const float* __restrict__ b2,
    const float* __restrict__ hin, float* __restrict__ hout,
    float* __restrict__ acc, int d)
{
    __shared__ __align__(16) unsigned char lds[49152];  // hs_T 32KB | g_T 16KB
    const int b   = blockIdx.x;
    const int t0  = blockIdx.y * TT;
    const int tid = threadIdx.x;
    const int w   = tid >> 6;
    const int l   = tid & 63;
    const int l15 = l & 15, lq = l >> 4;
    const int W   = TT + d;               // staged rows: j=0..W-1 -> h[..][t0-d+j]

    // ---- stage hs_T[j][ci] bf16 (swizzled); zeros left of t=0 ----
    #pragma unroll
    for (int pp = 0; pp < 8; ++pp) {
        const int cp = w*8 + pp;          // channel pair (2cp, 2cp+1)
        const float* s0 = hin + (size_t)(b*NCH + 2*cp)*NT;
        for (int j = l; j < W; j += 64) {
            const int g = t0 - d + j;
            float v0 = 0.0f, v1 = 0.0f;
            if (g >= 0) { v0 = s0[g]; v1 = s0[NT + g]; }
            const unsigned int pk = (unsigned int)f2bf(v0) | ((unsigned int)f2bf(v1) << 16);
            *(unsigned int*)(lds + HSW(j, 4*cp)) = pk;
        }
    }
    __syncthreads();

    // ---- phase 1: MFMA over K=128 (4 k-steps) ----
    s16x8 a1[2][4];
    #pragma unroll
    for (int mi = 0; mi < 2; ++mi)
        #pragma unroll
        for (int ks = 0; ks < 4; ++ks)
            a1[mi][ks] = *(const s16x8*)(w1p + (size_t)(((w*2 + mi)*4 + ks)*64 + l)*8);

    f32x4 accf[2][8];
    #pragma unroll
    for (int mi = 0; mi < 2; ++mi)
        #pragma unroll
        for (int nf = 0; nf < 8; ++nf)
            accf[mi][nf] = (f32x4){0.f, 0.f, 0.f, 0.f};

    #pragma unroll
    for (int nf = 0; nf < 8; ++nf) {
        #pragma unroll
        for (int ks = 0; ks < 4; ++ks) {
            const int tap = ks >> 1;
            const int j   = 16*nf + l15 + tap*d;
            const int cb  = 64*(ks & 1) + 16*lq;    // byte col = 2*ci0
            const s16x8 bf = *(const s16x8*)(lds + HSW(j, cb));
            accf[0][nf] = __builtin_amdgcn_mfma_f32_16x16x32_bf16(a1[0][ks], bf, accf[0][nf], 0, 0, 0);
            accf[1][nf] = __builtin_amdgcn_mfma_f32_16x16x32_bf16(a1[1][ks], bf, accf[1][nf], 0, 0, 0);
        }
    }

    // ---- gate + write g_T[t][c] bf16 (swizzled) ----
    float bt[4], bs[4];
    #pragma unroll
    for (int r = 0; r < 4; ++r) {
        const int co = 16*w + 4*lq + r;
        bt[r] = b1[co]; bs[r] = b1[64 + co];
    }
    #pragma unroll
    for (int nf = 0; nf < 8; ++nf) {
        unsigned short g[4];
        #pragma unroll
        for (int r = 0; r < 4; ++r) {
            const float gv = fast_tanh(accf[0][nf][r] + bt[r]) *
                             fast_sigmoid(accf[1][nf][r] + bs[r]);
            g[r] = f2bf(gv);
        }
        const int t  = 16*nf + l15;
        const int cb = 32*w + 8*lq;       // byte col = 2*(16w + 4lq)
        uint2 pk;
        pk.x = (unsigned int)g[0] | ((unsigned int)g[1] << 16);
        pk.y = (unsigned int)g[2] | ((unsigned int)g[3] << 16);
        *(uint2*)(lds + 32768 + HSW(t, cb)) = pk;
    }
    __syncthreads();

    // ---- phase 2: 1x1 MFMA (K=64, 2 k-steps) + residual epilogue ----
    s16x8 a2[2];
    #pragma unroll
    for (int ks = 0; ks < 2; ++ks)
        a2[ks] = *(const s16x8*)(w2p + (size_t)((w*2 + ks)*64 + l)*8);

    f32x4 acc2[8];
    #pragma unroll
    for (int nf = 0; nf < 8; ++nf) acc2[nf] = (f32x4){0.f, 0.f, 0.f, 0.f};

    #pragma unroll
    for (int nf = 0; nf < 8; ++nf) {
        #pragma unroll
        for (int ks = 0; ks < 2; ++ks) {
            const int j  = 16*nf + l15;
            const int cb = 64*ks + 16*lq;
            const s16x8 bf = *(const s16x8*)(lds + 32768 + HSW(j, cb));
            acc2[nf] = __builtin_amdgcn_mfma_f32_16x16x32_bf16(a2[ks], bf, acc2[nf], 0, 0, 0);
        }
    }

    float b2v[4];
    #pragma unroll
    for (int r = 0; r < 4; ++r) b2v[r] = b2[16*w + 4*lq + r];

    #pragma unroll
    for (int nf = 0; nf < 8; ++nf) {
        #pragma unroll
        for (int r = 0; r < 4; ++r) {
            const int co = 16*w + 4*lq + r;
            const size_t idx = (size_t)(b*NCH + co)*NT + t0 + 16*nf + l15;
            const float hn = acc2[nf][r] + b2v[r] + hin[idx];   // fp32 residual spine
            hout[idx] = hn;
            acc[idx] += hn;
        }
    }
}

// -------- head: agg=relu(acc/9); z=W_mid@agg; pi/mu/sigma --------
__global__ __launch_bounds__(256) void k_head(
    const float* __restrict__ acc,
    const float* __restrict__ w_mid, const float* __restrict__ b_mid,
    const float* __restrict__ w_pi,  const float* __restrict__ b_pi,
    const float* __restrict__ w_mu,  const float* __restrict__ b_mu,
    const float* __restrict__ w_sg,  const float* __restrict__ b_sg,
    float* __restrict__ out)
{
    __shared__ float aggs[NCH][256];
    const int b   = blockIdx.x;
    const int tid = threadIdx.x;
    const int t   = blockIdx.y * 256 + tid;
    const float inv9 = 1.0f / 9.0f;
    for (int c = 0; c < NCH; ++c) {
        float v = acc[(size_t)(b*NCH + c)*NT + t] * inv9;
        aggs[c][tid] = v > 0.0f ? v : 0.0f;
    }
    __syncthreads();

    float hd[10];
    #pragma unroll
    for (int o = 0; o < 10; ++o) hd[o] = 0.0f;

    for (int zc = 0; zc < 8; ++zc) {
        float z[16];
        #pragma unroll
        for (int i = 0; i < 16; ++i) z[i] = b_mid[zc*16 + i];
        for (int c = 0; c < NCH; ++c) {
            const float a = aggs[c][tid];
            const float* wr = w_mid + (zc*16)*NCH + c;
            #pragma unroll
            for (int i = 0; i < 16; ++i) z[i] += wr[i*NCH]*a;
        }
        #pragma unroll
        for (int i = 0; i < 16; ++i) {
            const int j = zc*16 + i;
            #pragma unroll
            for (int o = 0; o < 4; ++o) hd[o] += w_pi[o*128 + j]*z[i];
            #pragma unroll
            for (int o = 0; o < 3; ++o) {
                hd[4+o] += w_mu[o*128 + j]*z[i];
                hd[7+o] += w_sg[o*128 + j]*z[i];
            }
        }
    }

    const float p0 = hd[0] + b_pi[0], p1 = hd[1] + b_pi[1];
    const float p2 = hd[2] + b_pi[2], p3 = hd[3] + b_pi[3];
    const float m  = fmaxf(fmaxf(p0, p1), fmaxf(p2, p3));
    const float e0 = __expf(p0 - m), e1 = __expf(p1 - m);
    const float e2 = __expf(p2 - m), e3 = __expf(p3 - m);
    const float rs = fast_rcp(e0 + e1 + e2 + e3);
    const size_t piBase = (size_t)(b*4)*NT + t;
    out[piBase        ] = e0*rs;
    out[piBase +   NT ] = e1*rs;
    out[piBase + 2*NT ] = e2*rs;
    out[piBase + 3*NT ] = e3*rs;

    float* muO = out + (size_t)NB*4*NT;
    float* sgO = out + (size_t)NB*7*NT;
    #pragma unroll
    for (int o = 0; o < 3; ++o) {
        const float mv = hd[4+o] + b_mu[o];
        muO[(size_t)(b*3+o)*NT + t] = 2.0f * fast_tanh(0.5f * mv);
        const float sv = hd[7+o] + b_sg[o];
        sgO[(size_t)(b*3+o)*NT + t] = (sv > 15.0f) ? sv : logf(1.0f + __expf(sv));
    }
}

extern "C" void kernel_launch(void* const* d_in, const int* in_sizes, int n_in,
                              void* d_out, int out_size, void* d_ws, size_t ws_size,
                              hipStream_t stream)
{
    const float* x     = (const float*)d_in[0];
    const float* w_in  = (const float*)d_in[1];
    const float* b_in  = (const float*)d_in[2];
    const float* bw1   = (const float*)d_in[3];   // [8][128][64][2]
    const float* bb1   = (const float*)d_in[4];   // [8][128]
    const float* bw2   = (const float*)d_in[5];   // [8][64][64][1]
    const float* bb2   = (const float*)d_in[6];   // [8][64]
    const float* w_mid = (const float*)d_in[7];
    const float* b_mid = (const float*)d_in[8];
    const float* w_pi  = (const float*)d_in[9];
    const float* b_pi  = (const float*)d_in[10];
    const float* w_mu  = (const float*)d_in[11];
    const float* b_mu  = (const float*)d_in[12];
    const float* w_sg  = (const float*)d_in[13];
    const float* b_sg  = (const float*)d_in[14];
    float* out = (float*)d_out;

    const size_t tensSz = (size_t)NB * NCH * NT;  // 16,777,216 floats = 64 MB
    float* hA  = (float*)d_ws;
    float* hB  = hA + tensSz;
    float* acc = hB + tensSz;
    short* w1p = (short*)(acc + tensSz);          // 8*16384 shorts = 256 KB
    short* w2p = w1p + 8*16384;                   // 8*4096 shorts  = 64 KB

    k_pack<<<80, 256, 0, stream>>>(bw1, bw2, w1p, w2p);
    k_conv_in<<<dim3(NB, 16), 256, 0, stream>>>(x, w_in, b_in, hA, acc);

    static const int dil[8] = {1, 2, 4, 8, 16, 32, 64, 128};
    float* hin = hA; float* hout = hB;
    for (int i = 0; i < 8; ++i) {
        k_block<<<dim3(NB, NT/TT), 256, 0, stream>>>(
            w1p + (size_t)i*16384, bb1 + i*128,
            w2p + (size_t)i*4096,  bb2 + i*64,
            hin, hout, acc, dil[i]);
        float* tmp = hin; hin = hout; hout = tmp;
    }

    k_head<<<dim3(NB, 16), 256, 0, stream>>>(acc, w_mid, b_mid, w_pi, b_pi,
                                             w_mu, b_mu, w_sg, b_sg, out);
}

// Round 4
// 657.715 us; speedup vs baseline: 5.4664x; 1.3413x over previous
//
#include <hip/hip_runtime.h>
#include <math.h>

#define NB 64      // batch
#define NCH 64     // channels C
#define NT 4096    // time
#define TT 128     // k_block time tile

typedef float f32x4 __attribute__((ext_vector_type(4)));
typedef short s16x8 __attribute__((ext_vector_type(8)));

__device__ __forceinline__ float fast_rcp(float x) { return __builtin_amdgcn_rcpf(x); }
__device__ __forceinline__ float fast_sigmoid(float x) { return fast_rcp(1.0f + __expf(-x)); }
__device__ __forceinline__ float fast_tanh(float x) {
    return 1.0f - 2.0f * fast_rcp(__expf(2.0f * x) + 1.0f);
}
__device__ __forceinline__ unsigned short f2bf(float f) {   // RNE float->bf16
    unsigned int u = __builtin_bit_cast(unsigned int, f);
    u += 0x7fffu + ((u >> 16) & 1u);
    return (unsigned short)(u >> 16);
}

// swizzled LDS byte offset: row stride 128B, XOR bits 4-6 with row&7 (G4 fix)
#define HSW(j, cb) ((j)*128 + ((cb) ^ (((j)&7) << 4)))

// -------- weight pre-pack: fragment-ordered bf16 (runs every launch) --------
__global__ __launch_bounds__(256) void k_pack(
    const float* __restrict__ bw1, const float* __restrict__ bw2,
    short* __restrict__ w1p, short* __restrict__ w2p)
{
    const int id = blockIdx.x * 256 + threadIdx.x;
    if (id < 16384) {
        const int l = id & 63, ks = (id >> 6) & 3, mi = (id >> 8) & 1,
                  w = (id >> 9) & 3, L = id >> 11;
        const int co = 16*w + (l & 15) + 64*mi;
        short v[8];
        #pragma unroll
        for (int j = 0; j < 8; ++j) {
            const int k = 32*ks + 8*(l >> 4) + j;
            const int ci = k & 63, tap = k >> 6;
            v[j] = (short)f2bf(bw1[((size_t)(L*128 + co)*64 + ci)*2 + tap]);
        }
        *(s16x8*)(w1p + (size_t)id*8) = *(const s16x8*)v;
    } else if (id < 16384 + 4096) {
        const int id2 = id - 16384;
        const int l = id2 & 63, ks = (id2 >> 6) & 1, w = (id2 >> 7) & 3, L = id2 >> 9;
        const int co = 16*w + (l & 15);
        short v[8];
        #pragma unroll
        for (int j = 0; j < 8; ++j) {
            const int ci = 32*ks + 8*(l >> 4) + j;
            v[j] = (short)f2bf(bw2[(size_t)(L*64 + co)*64 + ci]);
        }
        *(s16x8*)(w2p + (size_t)id2*8) = *(const s16x8*)v;
    }
}

// -------- head-weight composition: Wc[10][64] = Whead@W_mid (with 1/9 folded), bc = Whead@b_mid + bhead --------
__global__ void k_compose(
    const float* __restrict__ w_mid, const float* __restrict__ b_mid,
    const float* __restrict__ w_pi,  const float* __restrict__ b_pi,
    const float* __restrict__ w_mu,  const float* __restrict__ b_mu,
    const float* __restrict__ w_sg,  const float* __restrict__ b_sg,
    float* __restrict__ wct, float* __restrict__ bc)
{
    const int tid = threadIdx.x;
    if (tid < 640) {
        const int o = tid >> 6, c = tid & 63;
        const float* wh = (o < 4) ? (w_pi + o*128)
                        : (o < 7) ? (w_mu + (o-4)*128) : (w_sg + (o-7)*128);
        float s = 0.f;
        for (int j = 0; j < 128; ++j) s += wh[j] * w_mid[j*64 + c];
        wct[c*10 + o] = s * (1.0f/9.0f);   // fold mean-of-9 into weights
    }
    if (tid < 10) {
        const int o = tid;
        const float* wh = (o < 4) ? (w_pi + o*128)
                        : (o < 7) ? (w_mu + (o-4)*128) : (w_sg + (o-7)*128);
        const float bh = (o < 4) ? b_pi[o] : (o < 7) ? b_mu[o-4] : b_sg[o-7];
        float s = bh;
        for (int j = 0; j < 128; ++j) s += wh[j] * b_mid[j];
        bc[o] = s;
    }
}

// -------- residual block via MFMA (layer 0 also fuses the input conv) --------
// flags: bit0 = first (acc = hin + hn), bit1 = last (skip hout), bit2 = input layer (hin is x)
__global__ __launch_bounds__(256, 4) void k_block(
    const short* __restrict__ w1p, const float* __restrict__ b1,
    const short* __restrict__ w2p, const float* __restrict__ b2,
    const float* __restrict__ w_in, const float* __restrict__ b_in,
    const float* __restrict__ hin, float* __restrict__ hout,
    float* __restrict__ acc, int d, int flags)
{
    __shared__ __align__(16) unsigned char lds[32768];  // hs (<=32KB) / g (16KB) / trbuf (32KB) overlaid
    const int b   = blockIdx.x;
    const int t0  = blockIdx.y * TT;
    const int tid = threadIdx.x;
    const int w   = tid >> 6;
    const int l   = tid & 63;
    const int l15 = l & 15, lq = l >> 4;
    const int W   = TT + d;
    const float inv = 1.0f / 4095.0f;
    const bool isFirst = flags & 1, isLast = flags & 2, isInput = flags & 4;

    // ---- stage hs_T[j][ci] bf16 (swizzled); zeros left of t=0 ----
    if (isInput) {
        // compute h0 = input conv of [x, linspace] directly (h0 never stored to HBM)
        const float* xb = hin + (size_t)b * NT;
        #pragma unroll
        for (int pp = 0; pp < 8; ++pp) {
            const int cp = w*8 + pp, c0 = 2*cp;
            const float w00=w_in[c0*4+0], w01=w_in[c0*4+1], w02=w_in[c0*4+2], w03=w_in[c0*4+3];
            const float w10=w_in[c0*4+4], w11=w_in[c0*4+5], w12=w_in[c0*4+6], w13=w_in[c0*4+7];
            const float b0=b_in[c0], b1v=b_in[c0+1];
            for (int j = l; j < W; j += 64) {
                const int g = t0 - 1 + j;      // input layer has d=1
                float v0 = 0.f, v1 = 0.f;
                if (g >= 0) {
                    const float x1v = xb[g];
                    const float x0v = (g > 0) ? xb[g-1] : 0.f;
                    const float l1v = (float)g * inv;
                    const float l0v = (g > 0) ? (float)(g-1) * inv : 0.f;
                    v0 = b0 + w00*x0v + w01*x1v + w02*l0v + w03*l1v;
                    v1 = b1v + w10*x0v + w11*x1v + w12*l0v + w13*l1v;
                }
                const unsigned int pk = (unsigned int)f2bf(v0) | ((unsigned int)f2bf(v1) << 16);
                *(unsigned int*)(lds + HSW(j, 4*cp)) = pk;
            }
        }
    } else {
        #pragma unroll
        for (int pp = 0; pp < 8; ++pp) {
            const int cp = w*8 + pp;
            const float* s0 = hin + (size_t)(b*NCH + 2*cp)*NT;
            for (int j = l; j < W; j += 64) {
                const int g = t0 - d + j;
                float v0 = 0.f, v1 = 0.f;
                if (g >= 0) { v0 = s0[g]; v1 = s0[NT + g]; }
                const unsigned int pk = (unsigned int)f2bf(v0) | ((unsigned int)f2bf(v1) << 16);
                *(unsigned int*)(lds + HSW(j, 4*cp)) = pk;
            }
        }
    }
    __syncthreads();

    // ---- phase 1: a[128][128t] = W1 @ taps, K=128 (4 k-steps) ----
    s16x8 a1[2][4];
    #pragma unroll
    for (int mi = 0; mi < 2; ++mi)
        #pragma unroll
        for (int ks = 0; ks < 4; ++ks)
            a1[mi][ks] = *(const s16x8*)(w1p + (size_t)(((w*2 + mi)*4 + ks)*64 + l)*8);

    f32x4 accf[2][8];
    #pragma unroll
    for (int mi = 0; mi < 2; ++mi)
        #pragma unroll
        for (int nf = 0; nf < 8; ++nf)
            accf[mi][nf] = (f32x4){0.f, 0.f, 0.f, 0.f};

    #pragma unroll
    for (int nf = 0; nf < 8; ++nf) {
        #pragma unroll
        for (int ks = 0; ks < 4; ++ks) {
            const int tap = ks >> 1;
            const int j   = 16*nf + l15 + tap*d;
            const int cb  = 64*(ks & 1) + 16*lq;
            const s16x8 bf = *(const s16x8*)(lds + HSW(j, cb));
            accf[0][nf] = __builtin_amdgcn_mfma_f32_16x16x32_bf16(a1[0][ks], bf, accf[0][nf], 0, 0, 0);
            accf[1][nf] = __builtin_amdgcn_mfma_f32_16x16x32_bf16(a1[1][ks], bf, accf[1][nf], 0, 0, 0);
        }
    }
    __syncthreads();   // all hs reads done before g overwrites region

    // ---- gate + write g_T[t][c] bf16 (swizzled, base of lds) ----
    float bt[4], bs[4];
    #pragma unroll
    for (int r = 0; r < 4; ++r) {
        const int co = 16*w + 4*lq + r;
        bt[r] = b1[co]; bs[r] = b1[64 + co];
    }
    #pragma unroll
    for (int nf = 0; nf < 8; ++nf) {
        unsigned short g[4];
        #pragma unroll
        for (int r = 0; r < 4; ++r) {
            const float gv = fast_tanh(accf[0][nf][r] + bt[r]) *
                             fast_sigmoid(accf[1][nf][r] + bs[r]);
            g[r] = f2bf(gv);
        }
        const int t  = 16*nf + l15;
        const int cb = 32*w + 8*lq;
        uint2 pk;
        pk.x = (unsigned int)g[0] | ((unsigned int)g[1] << 16);
        pk.y = (unsigned int)g[2] | ((unsigned int)g[3] << 16);
        *(uint2*)(lds + HSW(t, cb)) = pk;
    }
    __syncthreads();

    // ---- phase 2: 1x1 MFMA (K=64, 2 k-steps) ----
    s16x8 a2[2];
    #pragma unroll
    for (int ks = 0; ks < 2; ++ks)
        a2[ks] = *(const s16x8*)(w2p + (size_t)((w*2 + ks)*64 + l)*8);

    f32x4 acc2[8];
    #pragma unroll
    for (int nf = 0; nf < 8; ++nf) acc2[nf] = (f32x4){0.f, 0.f, 0.f, 0.f};

    #pragma unroll
    for (int nf = 0; nf < 8; ++nf) {
        #pragma unroll
        for (int ks = 0; ks < 2; ++ks) {
            const int j  = 16*nf + l15;
            const int cb = 64*ks + 16*lq;
            const s16x8 bf = *(const s16x8*)(lds + HSW(j, cb));
            acc2[nf] = __builtin_amdgcn_mfma_f32_16x16x32_bf16(a2[ks], bf, acc2[nf], 0, 0, 0);
        }
    }
    __syncthreads();   // all g reads done before trbuf overwrites region

    // ---- transpose conv-out (+bias) through LDS: trbuf[co][t] f32 ----
    float* tr = (float*)lds;
    {
        float b2v[4];
        #pragma unroll
        for (int r = 0; r < 4; ++r) b2v[r] = b2[16*w + 4*lq + r];
        #pragma unroll
        for (int nf = 0; nf < 8; ++nf)
            #pragma unroll
            for (int r = 0; r < 4; ++r)
                tr[(16*w + 4*lq + r)*TT + 16*nf + l15] = acc2[nf][r] + b2v[r];
    }
    __syncthreads();

    // ---- vectorized epilogue: hn = conv_out + h_prev; hout, acc (float4) ----
    {
        const int coB = (tid >> 5) * 8;
        const int t4  = (tid & 31) * 4;
        #pragma unroll
        for (int rr = 0; rr < 8; ++rr) {
            const int co = coB + rr;
            const size_t idx = (size_t)(b*NCH + co)*NT + t0 + t4;
            const f32x4 o4 = *(const f32x4*)(tr + co*TT + t4);
            f32x4 r4;
            if (isInput) {
                const float wa=w_in[co*4+0], wb=w_in[co*4+1],
                            wc2=w_in[co*4+2], wd=w_in[co*4+3], be=b_in[co];
                const float* xb = hin + (size_t)b*NT;
                #pragma unroll
                for (int i = 0; i < 4; ++i) {
                    const int tg = t0 + t4 + i;
                    const float x1v = xb[tg];
                    const float x0v = (tg > 0) ? xb[tg-1] : 0.f;
                    const float l1v = (float)tg * inv;
                    const float l0v = (tg > 0) ? (float)(tg-1)*inv : 0.f;
                    r4[i] = be + wa*x0v + wb*x1v + wc2*l0v + wd*l1v;
                }
            } else {
                r4 = *(const f32x4*)(hin + idx);
            }
            const f32x4 hn = o4 + r4;
            if (!isLast) *(f32x4*)(hout + idx) = hn;
            if (isFirst) {
                *(f32x4*)(acc + idx) = hn + r4;        // acc = h0 + h1
            } else {
                const f32x4 a4 = *(const f32x4*)(acc + idx);
                *(f32x4*)(acc + idx) = a4 + hn;
            }
        }
    }
}

// -------- head: out = Wc @ relu(acc) + bc, then softmax/tanh/softplus --------
__global__ __launch_bounds__(256) void k_head(
    const float* __restrict__ acc, const float* __restrict__ wct,
    const float* __restrict__ bc, float* __restrict__ out)
{
    const int b   = blockIdx.x;
    const int tid = threadIdx.x;
    const int t   = blockIdx.y * 256 + tid;

    float hd[10];
    #pragma unroll
    for (int o = 0; o < 10; ++o) hd[o] = bc[o];

    for (int c = 0; c < NCH; ++c) {
        const float v = acc[(size_t)(b*NCH + c)*NT + t];
        const float a = v > 0.f ? v : 0.f;          // 1/9 folded into wct
        const float* wr = wct + c*10;
        #pragma unroll
        for (int o = 0; o < 10; ++o) hd[o] += wr[o] * a;
    }

    const float m  = fmaxf(fmaxf(hd[0], hd[1]), fmaxf(hd[2], hd[3]));
    const float e0 = __expf(hd[0] - m), e1 = __expf(hd[1] - m);
    const float e2 = __expf(hd[2] - m), e3 = __expf(hd[3] - m);
    const float rs = fast_rcp(e0 + e1 + e2 + e3);
    const size_t piBase = (size_t)(b*4)*NT + t;
    out[piBase        ] = e0*rs;
    out[piBase +   NT ] = e1*rs;
    out[piBase + 2*NT ] = e2*rs;
    out[piBase + 3*NT ] = e3*rs;

    float* muO = out + (size_t)NB*4*NT;
    float* sgO = out + (size_t)NB*7*NT;
    #pragma unroll
    for (int o = 0; o < 3; ++o) {
        const float mv = hd[4+o];
        muO[(size_t)(b*3+o)*NT + t] = 2.0f * fast_tanh(0.5f * mv);
        const float sv = hd[7+o];
        sgO[(size_t)(b*3+o)*NT + t] = (sv > 15.0f) ? sv : logf(1.0f + __expf(sv));
    }
}

extern "C" void kernel_launch(void* const* d_in, const int* in_sizes, int n_in,
                              void* d_out, int out_size, void* d_ws, size_t ws_size,
                              hipStream_t stream)
{
    const float* x     = (const float*)d_in[0];
    const float* w_in  = (const float*)d_in[1];
    const float* b_in  = (const float*)d_in[2];
    const float* bw1   = (const float*)d_in[3];   // [8][128][64][2]
    const float* bb1   = (const float*)d_in[4];   // [8][128]
    const float* bw2   = (const float*)d_in[5];   // [8][64][64][1]
    const float* bb2   = (const float*)d_in[6];   // [8][64]
    const float* w_mid = (const float*)d_in[7];
    const float* b_mid = (const float*)d_in[8];
    const float* w_pi  = (const float*)d_in[9];
    const float* b_pi  = (const float*)d_in[10];
    const float* w_mu  = (const float*)d_in[11];
    const float* b_mu  = (const float*)d_in[12];
    const float* w_sg  = (const float*)d_in[13];
    const float* b_sg  = (const float*)d_in[14];
    float* out = (float*)d_out;

    const size_t tensSz = (size_t)NB * NCH * NT;  // 64 MB each
    float* hA  = (float*)d_ws;
    float* hB  = hA + tensSz;
    float* acc = hB + tensSz;
    short* w1p = (short*)(acc + tensSz);          // 256 KB
    short* w2p = w1p + 8*16384;                   // 64 KB
    float* wct = (float*)(w2p + 8*4096);          // 640 floats
    float* bcp = wct + 640;                       // 10 floats

    k_pack<<<80, 256, 0, stream>>>(bw1, bw2, w1p, w2p);
    k_compose<<<1, 1024, 0, stream>>>(w_mid, b_mid, w_pi, b_pi, w_mu, b_mu,
                                      w_sg, b_sg, wct, bcp);

    static const int dil[8] = {1, 2, 4, 8, 16, 32, 64, 128};
    // layer 0: input conv fused (hin = x), acc init; layer 7: no hout store
    k_block<<<dim3(NB, NT/TT), 256, 0, stream>>>(
        w1p, bb1, w2p, bb2, w_in, b_in, x, hA, acc, dil[0], 1 | 4);
    float* hin = hA; float* hout = hB;
    for (int i = 1; i < 8; ++i) {
        const int flags = (i == 7) ? 2 : 0;
        k_block<<<dim3(NB, NT/TT), 256, 0, stream>>>(
            w1p + (size_t)i*16384, bb1 + i*128,
            w2p + (size_t)i*4096,  bb2 + i*64,
            w_in, b_in, hin, hout, acc, dil[i], flags);
        float* tmp = hin; hin = hout; hout = tmp;
    }

    k_head<<<dim3(NB, 16), 256, 0, stream>>>(acc, wct, bcp, out);
}

// Round 6
// 377.018 us; speedup vs baseline: 9.5362x; 1.7445x over previous
//
#include <hip/hip_runtime.h>
#include <math.h>

#define NB 64      // batch
#define NCH 64     // channels C
#define NT 4096    // time
#define TOUT 512   // output timesteps per block
#define ROWS 768   // staged rows = TOUT + 256 halo (receptive field 255)

typedef float f32x4 __attribute__((ext_vector_type(4)));
typedef short s16x8 __attribute__((ext_vector_type(8)));

__device__ __forceinline__ float fast_rcp(float x) { return __builtin_amdgcn_rcpf(x); }
__device__ __forceinline__ float fast_sigmoid(float x) { return fast_rcp(1.0f + __expf(-x)); }
__device__ __forceinline__ float fast_tanh(float x) {
    return 1.0f - 2.0f * fast_rcp(__expf(2.0f * x) + 1.0f);
}
__device__ __forceinline__ unsigned short f2bf(float f) {   // RNE float->bf16
    unsigned int u = __builtin_bit_cast(unsigned int, f);
    u += 0x7fffu + ((u >> 16) & 1u);
    return (unsigned short)(u >> 16);
}
__device__ __forceinline__ float bf2f_lo(unsigned int u) { return __builtin_bit_cast(float, u << 16); }
__device__ __forceinline__ float bf2f_hi(unsigned int u) { return __builtin_bit_cast(float, u & 0xffff0000u); }

// swizzled LDS byte offset: row stride 128B, XOR bits 4-6 with row&7 (G4 fix)
#define HSW(j, cb) ((j)*128 + ((cb) ^ (((j)&7) << 4)))

// LDS map: hs [768 rows x 128B] @0 (96KB) | gbuf [128 x 128B] @98304 (16KB, also xs/red overlay) | wct @118784 (2.5KB)
#define OFF_GB  98304
#define OFF_RED 98304
#define OFF_WCT 118784
#define LDS_SZ  121344

// -------- weight pre-pack: fragment-ordered bf16 --------
// w1p: [L][g4][mi2][ks4][lane64][8]  A[co][k], co=16g+(l&15)+64mi, k=32ks+8(l>>4)+j
//      k = ci + 64*tap  (ci=k&63, tap=k>>6; tap0 = t-d, tap1 = t)
// w2p: [L][g4][ks2][lane64][8]       A[co][ci], co=16g+(l&15), ci=32ks+8(l>>4)+j
__global__ __launch_bounds__(256) void k_pack(
    const float* __restrict__ bw1, const float* __restrict__ bw2,
    short* __restrict__ w1p, short* __restrict__ w2p)
{
    const int id = blockIdx.x * 256 + threadIdx.x;
    if (id < 16384) {
        const int l = id & 63, ks = (id >> 6) & 3, mi = (id >> 8) & 1,
                  g = (id >> 9) & 3, L = id >> 11;
        const int co = 16*g + (l & 15) + 64*mi;
        short v[8];
        #pragma unroll
        for (int j = 0; j < 8; ++j) {
            const int k = 32*ks + 8*(l >> 4) + j;
            const int ci = k & 63, tap = k >> 6;
            v[j] = (short)f2bf(bw1[((size_t)(L*128 + co)*64 + ci)*2 + tap]);
        }
        *(s16x8*)(w1p + (size_t)id*8) = *(const s16x8*)v;
    } else if (id < 16384 + 4096) {
        const int id2 = id - 16384;
        const int l = id2 & 63, ks = (id2 >> 6) & 1, g = (id2 >> 7) & 3, L = id2 >> 9;
        const int co = 16*g + (l & 15);
        short v[8];
        #pragma unroll
        for (int j = 0; j < 8; ++j) {
            const int ci = 32*ks + 8*(l >> 4) + j;
            v[j] = (short)f2bf(bw2[(size_t)(L*64 + co)*64 + ci]);
        }
        *(s16x8*)(w2p + (size_t)id2*8) = *(const s16x8*)v;
    }
}

// -------- head-weight composition: Wc[64][10] (1/9 folded), bc[10] --------
__global__ void k_compose(
    const float* __restrict__ w_mid, const float* __restrict__ b_mid,
    const float* __restrict__ w_pi,  const float* __restrict__ b_pi,
    const float* __restrict__ w_mu,  const float* __restrict__ b_mu,
    const float* __restrict__ w_sg,  const float* __restrict__ b_sg,
    float* __restrict__ wct, float* __restrict__ bc)
{
    const int tid = threadIdx.x;
    if (tid < 640) {
        const int o = tid >> 6, c = tid & 63;
        const float* wh = (o < 4) ? (w_pi + o*128)
                        : (o < 7) ? (w_mu + (o-4)*128) : (w_sg + (o-7)*128);
        float s = 0.f;
        for (int j = 0; j < 128; ++j) s += wh[j] * w_mid[j*64 + c];
        wct[c*10 + o] = s * (1.0f/9.0f);
    }
    if (tid < 10) {
        const int o = tid;
        const float* wh = (o < 4) ? (w_pi + o*128)
                        : (o < 7) ? (w_mu + (o-4)*128) : (w_sg + (o-7)*128);
        const float bh = (o < 4) ? b_pi[o] : (o < 7) ? b_mu[o-4] : b_sg[o-7];
        float s = bh;
        for (int j = 0; j < 128; ++j) s += wh[j] * b_mid[j];
        bc[o] = s;
    }
}

// One 128-t chunk of one layer, fully in LDS. Decreasing-base order makes
// in-place hs update safe. USEREG selects fp32 register residual (output rows).
// ZERO-PAD FIX: stored h for rows with global t<0 (t0+r<256) is forced to
// exactly 0 so every layer's causal pad reads true zeros (reference semantics).
#define CHUNK_BODY(TC, USEREG, CC)                                              \
  {                                                                             \
    f32x4 accf0[4], accf1[4];                                                   \
    _Pragma("unroll")                                                           \
    for (int nf = 0; nf < 4; ++nf) {                                            \
      accf0[nf] = (f32x4){0.f,0.f,0.f,0.f};                                     \
      accf1[nf] = (f32x4){0.f,0.f,0.f,0.f};                                     \
    }                                                                           \
    _Pragma("unroll")                                                           \
    for (int nf = 0; nf < 4; ++nf) {                                            \
      const int rb = (TC) + 64*th + 16*nf + l15;                                \
      _Pragma("unroll")                                                         \
      for (int ks = 0; ks < 4; ++ks) {                                          \
        int jr = rb - d + (ks >> 1)*d;   /* tap0: r-d, tap1: r */               \
        jr = jr < 0 ? 0 : jr;            /* garbage-region clamp (finite) */    \
        const int cb = 64*(ks & 1) + 16*lq;                                     \
        const s16x8 bf = *(const s16x8*)(lds + HSW(jr, cb));                    \
        accf0[nf] = __builtin_amdgcn_mfma_f32_16x16x32_bf16(a1[0][ks], bf, accf0[nf], 0,0,0); \
        accf1[nf] = __builtin_amdgcn_mfma_f32_16x16x32_bf16(a1[1][ks], bf, accf1[nf], 0,0,0); \
      }                                                                         \
    }                                                                           \
    _Pragma("unroll")                                                           \
    for (int nf = 0; nf < 4; ++nf) {                                            \
      const int tl = 64*th + 16*nf + l15;                                       \
      unsigned short gg[4];                                                     \
      _Pragma("unroll")                                                         \
      for (int rr = 0; rr < 4; ++rr)                                            \
        gg[rr] = f2bf(fast_tanh(accf0[nf][rr] + bt[rr]) *                       \
                      fast_sigmoid(accf1[nf][rr] + bs[rr]));                    \
      uint2 pk;                                                                 \
      pk.x = (unsigned int)gg[0] | ((unsigned int)gg[1] << 16);                 \
      pk.y = (unsigned int)gg[2] | ((unsigned int)gg[3] << 16);                 \
      *(uint2*)(lds + OFF_GB + HSW(tl, 2*cobase)) = pk;                         \
    }                                                                           \
    __syncthreads();                                                            \
    f32x4 c2[4];                                                                \
    _Pragma("unroll")                                                           \
    for (int nf = 0; nf < 4; ++nf) c2[nf] = (f32x4){0.f,0.f,0.f,0.f};           \
    _Pragma("unroll")                                                           \
    for (int nf = 0; nf < 4; ++nf) {                                            \
      const int tl = 64*th + 16*nf + l15;                                       \
      _Pragma("unroll")                                                         \
      for (int ks = 0; ks < 2; ++ks) {                                          \
        const int cb = 64*ks + 16*lq;                                           \
        const s16x8 bf = *(const s16x8*)(lds + OFF_GB + HSW(tl, cb));           \
        c2[nf] = __builtin_amdgcn_mfma_f32_16x16x32_bf16(a2[ks], bf, c2[nf], 0,0,0); \
      }                                                                         \
    }                                                                           \
    _Pragma("unroll")                                                           \
    for (int nf = 0; nf < 4; ++nf) {                                            \
      const int r  = (TC) + 64*th + 16*nf + l15;                                \
      const int ha = HSW(r, 2*cobase);                                          \
      f32x4 resid;                                                              \
      if (USEREG) {                                                             \
        resid = h_reg[CC][nf];                                                  \
      } else {                                                                  \
        const uint2 hp = *(const uint2*)(lds + ha);                             \
        resid[0] = bf2f_lo(hp.x); resid[1] = bf2f_hi(hp.x);                     \
        resid[2] = bf2f_lo(hp.y); resid[3] = bf2f_hi(hp.y);                     \
      }                                                                         \
      f32x4 hn;                                                                 \
      _Pragma("unroll")                                                         \
      for (int rr = 0; rr < 4; ++rr) hn[rr] = c2[nf][rr] + b2v[rr] + resid[rr]; \
      if (USEREG) {                                                             \
        h_reg[CC][nf] = hn;                                                     \
        _Pragma("unroll")                                                       \
        for (int rr = 0; rr < 4; ++rr) acc_reg[CC][nf][rr] += hn[rr];           \
      }                                                                         \
      uint2 po;                                                                 \
      po.x = (unsigned int)f2bf(hn[0]) | ((unsigned int)f2bf(hn[1]) << 16);     \
      po.y = (unsigned int)f2bf(hn[2]) | ((unsigned int)f2bf(hn[3]) << 16);     \
      if (t0 + r < 256) { po.x = 0u; po.y = 0u; }  /* preserve causal zero-pad */ \
      *(uint2*)(lds + ha) = po;                                                 \
    }                                                                           \
    __syncthreads();                                                            \
  }

// -------- mega kernel: input conv + 8 gated residual layers + head --------
__global__ __launch_bounds__(512, 2) void k_mega(
    const short* __restrict__ w1p, const float* __restrict__ bb1,
    const short* __restrict__ w2p, const float* __restrict__ bb2,
    const float* __restrict__ w_in, const float* __restrict__ b_in,
    const float* __restrict__ x,
    const float* __restrict__ wct, const float* __restrict__ bc,
    float* __restrict__ out)
{
    __shared__ __align__(16) unsigned char lds[LDS_SZ];
    const int b   = blockIdx.x;
    const int t0  = blockIdx.y * TOUT;
    const int tid = threadIdx.x;
    const int w   = tid >> 6;          // 8 waves
    const int l   = tid & 63;
    const int l15 = l & 15, lq = l >> 4;
    const int wg  = w & 3;             // co group
    const int th  = w >> 2;            // t half of 128-chunk
    const int cobase = 16*wg + 4*lq;   // C/D frag rows: cobase + rr
    const float inv = 1.0f / 4095.0f;

    // ---- stage xs[769] = x[t0-257 .. t0+511] (zeros left of 0) ----
    float* xs = (float*)(lds + OFF_GB);
    for (int idx = tid; idx < ROWS + 1; idx += 512) {
        const int t = t0 - 257 + idx;
        xs[idx] = (t >= 0) ? x[(size_t)b*NT + t] : 0.f;
    }
    __syncthreads();

    // ---- h0 (input conv) into hs bf16, all 768 rows ----
    #pragma unroll
    for (int pp = 0; pp < 4; ++pp) {
        const int cp = w*4 + pp, c0 = 2*cp;
        const float wa0=w_in[c0*4+0], wa1=w_in[c0*4+1], wa2=w_in[c0*4+2], wa3=w_in[c0*4+3], ba=b_in[c0];
        const float wb0=w_in[c0*4+4], wb1=w_in[c0*4+5], wb2=w_in[c0*4+6], wb3=w_in[c0*4+7], bb=b_in[c0+1];
        for (int j = l; j < ROWS; j += 64) {
            const int t = t0 - 256 + j;
            float v0 = 0.f, v1 = 0.f;
            if (t >= 0) {
                const float x1v = xs[j+1], x0v = xs[j];
                const float l1v = (float)t * inv;
                const float l0v = (t > 0) ? (float)(t-1)*inv : 0.f;
                v0 = ba + wa0*x0v + wa1*x1v + wa2*l0v + wa3*l1v;
                v1 = bb + wb0*x0v + wb1*x1v + wb2*l0v + wb3*l1v;
            }
            *(unsigned int*)(lds + HSW(j, 4*cp)) =
                (unsigned int)f2bf(v0) | ((unsigned int)f2bf(v1) << 16);
        }
    }

    // ---- fp32 h/acc registers for the 512 output rows (this thread's frags) ----
    f32x4 h_reg[4][4], acc_reg[4][4];
    {
        float wi0[4], wi1[4], wi2[4], wi3[4], bi[4];
        #pragma unroll
        for (int rr = 0; rr < 4; ++rr) {
            const int co = cobase + rr;
            wi0[rr]=w_in[co*4+0]; wi1[rr]=w_in[co*4+1];
            wi2[rr]=w_in[co*4+2]; wi3[rr]=w_in[co*4+3]; bi[rr]=b_in[co];
        }
        #pragma unroll
        for (int cc = 0; cc < 4; ++cc) {
            #pragma unroll
            for (int nf = 0; nf < 4; ++nf) {
                const int j = 256 + 128*cc + 64*th + 16*nf + l15;
                const int t = t0 - 256 + j;          // >= 0 always
                const float x1v = xs[j+1], x0v = xs[j];
                const float l1v = (float)t * inv;
                const float l0v = (t > 0) ? (float)(t-1)*inv : 0.f;
                f32x4 hv;
                #pragma unroll
                for (int rr = 0; rr < 4; ++rr)
                    hv[rr] = bi[rr] + wi0[rr]*x0v + wi1[rr]*x1v + wi2[rr]*l0v + wi3[rr]*l1v;
                h_reg[cc][nf] = hv;
                acc_reg[cc][nf] = hv;                // acc tap 0 = h0
            }
        }
    }
    __syncthreads();   // hs complete; xs region free for gbuf

    // ---- 8 layers, in-place in hs, chunks processed high-to-low ----
    for (int li = 0; li < 8; ++li) {
        const int d = 1 << li;
        const short* w1l = w1p + li*16384;
        const short* w2l = w2p + li*4096;
        s16x8 a1[2][4], a2[2];
        #pragma unroll
        for (int mi = 0; mi < 2; ++mi)
            #pragma unroll
            for (int ks = 0; ks < 4; ++ks)
                a1[mi][ks] = *(const s16x8*)(w1l + (size_t)(((wg*2 + mi)*4 + ks)*64 + l)*8);
        #pragma unroll
        for (int ks = 0; ks < 2; ++ks)
            a2[ks] = *(const s16x8*)(w2l + (size_t)((wg*2 + ks)*64 + l)*8);
        float bt[4], bs[4], b2v[4];
        #pragma unroll
        for (int rr = 0; rr < 4; ++rr) {
            bt[rr]  = bb1[li*128 + cobase + rr];
            bs[rr]  = bb1[li*128 + 64 + cobase + rr];
            b2v[rr] = bb2[li*64 + cobase + rr];
        }

        // output chunks (register residual), high base first
        #pragma unroll
        for (int cci = 0; cci < 4; ++cci) {
            const int cc = 3 - cci;
            CHUNK_BODY(256 + 128*cc, 1, cc)
        }
        // halo chunks (bf16 LDS residual); rows below validity are garbage-but-finite
        if (li <= 6) CHUNK_BODY(128, 0, 0)
        if (li <= 5) CHUNK_BODY(0,   0, 0)
    }

    // ---- fused head: out = nonlin(Wc @ relu(acc) + bc) ----
    float* wcl = (float*)(lds + OFF_WCT);
    for (int i = tid; i < 640; i += 512) wcl[i] = wct[i];
    __syncthreads();
    float* red = (float*)(lds + OFF_RED);   // [wg4][tl128][10]
    #pragma unroll
    for (int cc = 0; cc < 4; ++cc) {
        #pragma unroll
        for (int nf = 0; nf < 4; ++nf) {
            float p[10];
            #pragma unroll
            for (int o = 0; o < 10; ++o) p[o] = 0.f;
            #pragma unroll
            for (int rr = 0; rr < 4; ++rr) {
                float a = acc_reg[cc][nf][rr];
                a = a > 0.f ? a : 0.f;
                const float* wr = wcl + (cobase + rr)*10;
                #pragma unroll
                for (int o = 0; o < 10; ++o) p[o] += wr[o] * a;
            }
            #pragma unroll
            for (int o = 0; o < 10; ++o) {      // reduce over lq (4 lanes)
                p[o] += __shfl_xor(p[o], 16, 64);
                p[o] += __shfl_xor(p[o], 32, 64);
            }
            if (lq == 0) {
                const int tl = 64*th + 16*nf + l15;
                #pragma unroll
                for (int o = 0; o < 10; ++o) red[(wg*128 + tl)*10 + o] = p[o];
            }
        }
        __syncthreads();
        if (tid < 128) {
            float hd[10];
            #pragma unroll
            for (int o = 0; o < 10; ++o)
                hd[o] = bc[o] + red[(0*128+tid)*10+o] + red[(1*128+tid)*10+o]
                              + red[(2*128+tid)*10+o] + red[(3*128+tid)*10+o];
            const int t = t0 + 128*cc + tid;
            const float m  = fmaxf(fmaxf(hd[0], hd[1]), fmaxf(hd[2], hd[3]));
            const float e0 = __expf(hd[0]-m), e1 = __expf(hd[1]-m);
            const float e2 = __expf(hd[2]-m), e3 = __expf(hd[3]-m);
            const float rs = fast_rcp(e0+e1+e2+e3);
            const size_t piBase = (size_t)(b*4)*NT + t;
            out[piBase       ] = e0*rs;
            out[piBase +  NT ] = e1*rs;
            out[piBase + 2*NT] = e2*rs;
            out[piBase + 3*NT] = e3*rs;
            float* muO = out + (size_t)NB*4*NT;
            float* sgO = out + (size_t)NB*7*NT;
            #pragma unroll
            for (int o = 0; o < 3; ++o) {
                muO[(size_t)(b*3+o)*NT + t] = 2.0f * fast_tanh(0.5f * hd[4+o]);
                const float sv = hd[7+o];
                sgO[(size_t)(b*3+o)*NT + t] = (sv > 15.0f) ? sv : logf(1.0f + __expf(sv));
            }
        }
        __syncthreads();
    }
}

extern "C" void kernel_launch(void* const* d_in, const int* in_sizes, int n_in,
                              void* d_out, int out_size, void* d_ws, size_t ws_size,
                              hipStream_t stream)
{
    const float* x     = (const float*)d_in[0];
    const float* w_in  = (const float*)d_in[1];
    const float* b_in  = (const float*)d_in[2];
    const float* bw1   = (const float*)d_in[3];   // [8][128][64][2]
    const float* bb1   = (const float*)d_in[4];   // [8][128]
    const float* bw2   = (const float*)d_in[5];   // [8][64][64][1]
    const float* bb2   = (const float*)d_in[6];   // [8][64]
    const float* w_mid = (const float*)d_in[7];
    const float* b_mid = (const float*)d_in[8];
    const float* w_pi  = (const float*)d_in[9];
    const float* b_pi  = (const float*)d_in[10];
    const float* w_mu  = (const float*)d_in[11];
    const float* b_mu  = (const float*)d_in[12];
    const float* w_sg  = (const float*)d_in[13];
    const float* b_sg  = (const float*)d_in[14];
    float* out = (float*)d_out;

    short* w1p = (short*)d_ws;                    // 262144 B
    short* w2p = w1p + 8*16384;                   // 65536 B
    float* wct = (float*)(w2p + 8*4096);          // 640 floats
    float* bcp = wct + 640;                       // 10 floats

    k_pack<<<80, 256, 0, stream>>>(bw1, bw2, w1p, w2p);
    k_compose<<<1, 1024, 0, stream>>>(w_mid, b_mid, w_pi, b_pi, w_mu, b_mu,
                                      w_sg, b_sg, wct, bcp);
    k_mega<<<dim3(NB, NT/TOUT), 512, 0, stream>>>(
        w1p, bb1, w2p, bb2, w_in, b_in, x, wct, bcp, out);
}